// Round 3
// baseline (290.529 us; speedup 1.0000x reference)
//
#include <hip/hip_runtime.h>
#include <math.h>

#define NB 16
#define NC 8
#define HH 512
#define WW 512
#define HW (HH * WW)
#define CHW (NC * HW)

#define LOG2E 1.44269504088896f
#define LN2   0.693147180559945f
#define CLMP  144.269504088896f   /* 100 * log2(e): clamp in log2 units */

__device__ __forceinline__ float sigf(float x) {
    return __builtin_amdgcn_rcpf(1.0f + __builtin_amdgcn_exp2f(-x * LOG2E));
}

__device__ __forceinline__ void ld4(const float* p, float* o) {
    float4 v = *(const float4*)p;
    o[0] = v.x; o[1] = v.y; o[2] = v.z; o[3] = v.w;
}

// R3: max memory-level parallelism. R2 evidence: VGPR=60 (launch_bounds
// min-waves=4) forced the compiler to issue the 23 float4 loads in tiny
// just-in-time batches -> ~2 loads in flight per CU (Little's law from the
// observed 1.66 TB/s at ~700cy latency) -> latency-serialized at 27% VALU.
// Fix: launch_bounds(256,2) lifts the VGPR ceiling; ALL loads are hoisted
// to the top in consumption order so each wave pays ONE latency round-trip
// with ~23KB in flight. Everything else (numerics, shuffles, masks) is
// identical to the R2 kernel that passed with absmax 0.
__global__ __launch_bounds__(256, 2) void bicon_loss_kernel(
    const float* __restrict__ c_map,
    const float* __restrict__ target,
    const float* __restrict__ con_target,
    float* __restrict__ out)
{
    const int tid  = threadIdx.x;
    const int lane = tid & 63;
    const int wave = tid >> 6;
    const int t    = blockIdx.x * 256 + tid;
    const int g    = t >> 7;          // global row id: 0 .. 16*512-1
    const int b    = g >> 9;
    const int row  = g & 511;
    const int px0  = (t & 127) << 2;  // 0..508, contiguous within a wave

    const bool hu = row > 0, hd = row < HH - 1;
    const bool wl = px0 > 0, wr = px0 < WW - 4;
    const int rU = hu ? row - 1 : 0;      // clamped; values gated at use
    const int rD = hd ? row + 1 : HH - 1;

    const float* base = c_map + b * CHW;
    const int ro = row * WW + px0;
    const float* cm = base + ro;
    const float* ct = con_target + b * CHW + ro;

    // ================= hoisted load phase: 23 x float4 =================
    float cv[8][4];
    #pragma unroll
    for (int c = 0; c < 8; ++c) ld4(cm + c * HW, cv[c]);

    float tvf[8][4];
    #pragma unroll
    for (int c = 0; c < 8; ++c) ld4(ct + c * HW, tvf[c]);

    float u5r[4], u6r[4], u7r[4], d0r[4], d1r[4], d2r[4];
    ld4(base + 5 * HW + rU * WW + px0, u5r);
    ld4(base + 6 * HW + rU * WW + px0, u6r);
    ld4(base + 7 * HW + rU * WW + px0, u7r);
    ld4(base + 0 * HW + rD * WW + px0, d0r);
    ld4(base + 1 * HW + rD * WW + px0, d1r);
    ld4(base + 2 * HW + rD * WW + px0, d2r);

    float tg[4];
    ld4(target + b * HW + ro, tg);

    // wave-boundary edge scalars (2 lanes per wave)
    const bool atL = (lane == 0)  && wl;
    const bool atR = (lane == 63) && wr;
    float eL7 = 0.f, eL0 = 0.f, eL4 = 0.f, eR5 = 0.f, eR2 = 0.f, eR3 = 0.f;
    if (atL) {
        eL7 = base[7 * HW + rU  * WW + px0 - 1];
        eL0 = base[0 * HW + rD  * WW + px0 - 1];
        eL4 = base[4 * HW + row * WW + px0 - 1];
    }
    if (atR) {
        eR5 = base[5 * HW + rU  * WW + px0 + 4];
        eR2 = base[2 * HW + rD  * WW + px0 + 4];
        eR3 = base[3 * HW + row * WW + px0 + 4];
    }

    // ================= compute phase =================
    // center: sigmoid + fused conmap BCE, one exp+log per element
    //   -log2 p = log2(1+e), -log2(1-p) = c*log2e + log2(1+e), e = 2^(-c*log2e)
    float sp[8][4];
    int msk[4] = {0, 0, 0, 0};
    float acc_con = 0.0f;                       // log2 units
    #pragma unroll
    for (int c = 0; c < 8; ++c) {
        #pragma unroll
        for (int j = 0; j < 4; ++j) {
            const float cl2 = cv[c][j] * LOG2E;
            const float e   = __builtin_amdgcn_exp2f(-cl2);
            const float s   = 1.0f + e;
            const float Lg  = __builtin_amdgcn_logf(s);   // -log2(p)
            sp[c][j] = __builtin_amdgcn_rcpf(s);          // p
            const bool one = tvf[c][j] > 0.5f;
            msk[j] |= (int)one << c;
            acc_con += fminf(Lg + (one ? 0.0f : cl2), CLMP);
        }
    }

    // in-wave x-shift edges via lane shuffles (uniform control flow)
    float u5n = __shfl_down(u5r[0], 1, 64); if (lane == 63) u5n = eR5;
    float u7p = __shfl_up (u7r[3], 1, 64); if (lane == 0)  u7p = eL7;
    float d2n = __shfl_down(d2r[0], 1, 64); if (lane == 63) d2n = eR2;
    float d0p = __shfl_up (d0r[3], 1, 64); if (lane == 0)  d0p = eL0;
    float sp4p = __shfl_up (sp[4][3], 1, 64); if (lane == 0)  sp4p = sigf(eL4);
    float sp3n = __shfl_down(sp[3][0], 1, 64); if (lane == 63) sp3n = sigf(eR3);

    float acc_bi = 0.0f, acc_de = 0.0f;         // log2 units
    #pragma unroll
    for (int j = 0; j < 4; ++j) {
        const float n6  = hu ? sigf(u6r[j]) : 0.0f;
        const float n5  = (((j < 3) ? hu : (hu && wr)))
                          ? sigf((j < 3) ? u5r[j + 1] : u5n) : 0.0f;
        const float n7  = (((j > 0) ? hu : (hu && wl)))
                          ? sigf((j > 0) ? u7r[j - 1] : u7p) : 0.0f;
        const float dn1 = hd ? sigf(d1r[j]) : 0.0f;
        const float dn2 = (((j < 3) ? hd : (hd && wr)))
                          ? sigf((j < 3) ? d2r[j + 1] : d2n) : 0.0f;
        const float dn0 = (((j > 0) ? hd : (hd && wl)))
                          ? sigf((j > 0) ? d0r[j - 1] : d0p) : 0.0f;
        const float m4  = (j > 0) ? sp[4][j - 1] : (wl ? sp4p : 0.0f);
        const float m3  = (j < 3) ? sp[3][j + 1] : (wr ? sp3n : 0.0f);

        const float a1 = sp[3][j] * m4;    // c3 * shift_right(c4)
        const float a2 = sp[4][j] * m3;    // c4 * shift_left(c3)
        const float a3 = sp[1][j] * n6;    // c1 * shift_down(c6)
        const float a4 = sp[6][j] * dn1;   // c6 * shift_up(c1)
        const float a5 = sp[2][j] * n5;    // c2 * left-bottom(c5)
        const float a6 = sp[5][j] * dn2;   // c5 * right-above(c2)
        const float a7 = sp[0][j] * n7;    // c0 * right-bottom(c7)
        const float a8 = sp[7][j] * dn0;   // c7 * left-above(c0)

        const float vote[8] = { a7, a3, a5, a1, a2, a6, a4, a8 };
        const int m = msk[j];

        #pragma unroll
        for (int c = 0; c < 8; ++c) {
            const bool one = (m >> c) & 1;
            const float q = one ? vote[c] : (1.0f - vote[c]);
            acc_bi += fminf(-__builtin_amdgcn_logf(q), CLMP);
        }

        const float glo = (a1 + a2 + a3 + a4 + a5 + a6 + a7 + a8) * 0.125f;
        float mn = vote[0];
        #pragma unroll
        for (int c = 1; c < 8; ++c) mn = fminf(mn, vote[c]);

        const bool edge = (m != 0) && (m != 255);
        const float dec = edge ? (1.0f - mn) : glo;
        const float qd  = (tg[j] > 0.5f) ? dec : (1.0f - dec);
        acc_de += fminf(-__builtin_amdgcn_logf(qd), CLMP);
    }

    float local = fmaf(0.8f, acc_con, fmaf(0.2f, acc_bi, acc_de)) * LN2;

    // ---- reduction: wave64 shuffle -> 4-float LDS -> one atomic ----
    #pragma unroll
    for (int off = 32; off > 0; off >>= 1)
        local += __shfl_down(local, off, 64);

    __shared__ float wsum[4];
    if (lane == 0) wsum[wave] = local;
    __syncthreads();
    if (tid == 0)
        atomicAdd(out, (wsum[0] + wsum[1]) + (wsum[2] + wsum[3]));
}

extern "C" void kernel_launch(void* const* d_in, const int* in_sizes, int n_in,
                              void* d_out, int out_size, void* d_ws, size_t ws_size,
                              hipStream_t stream) {
    const float* c_map      = (const float*)d_in[0];
    const float* target     = (const float*)d_in[1];
    const float* con_target = (const float*)d_in[2];
    float* out = (float*)d_out;

    hipMemsetAsync(out, 0, sizeof(float), stream);

    const int blocks = NB * (HH / 2);   // 4096 blocks x 256 thr, 4 px/thread
    bicon_loss_kernel<<<blocks, 256, 0, stream>>>(c_map, target, con_target, out);
}

// Round 4
// 285.882 us; speedup vs baseline: 1.0163x; 1.0163x over previous
//
#include <hip/hip_runtime.h>
#include <math.h>

#define NB 16
#define NC 8
#define HH 512
#define WW 512
#define HW (HH * WW)
#define CHW (NC * HW)

#define LOG2E 1.44269504088896f
#define LN2   0.693147180559945f
#define CLMP  144.269504088896f   /* 100 * log2(e): clamp in log2 units */

__device__ __forceinline__ float sigf(float x) {
    return __builtin_amdgcn_rcpf(1.0f + __builtin_amdgcn_exp2f(-x * LOG2E));
}

__device__ __forceinline__ void ld4(const float* p, float* o) {
    float4 v = *(const float4*)p;
    o[0] = v.x; o[1] = v.y; o[2] = v.z; o[3] = v.w;
}

// R4: R3's source-level load hoist was silently undone by the compiler
// (VGPR stayed 60 -> loads re-sunk into just-in-time batches -> ~12 serial
// latency round-trips per wave). Fix: __builtin_amdgcn_sched_barrier(0)
// after the load phase pins ALL loads before ANY compute; their results
// stay live across the fence, so the wave has ~29 loads in flight at once
// and pays one latency round-trip. Loads are issued first-used-first so
// counted vmcnt waits let the center pass start while halo is in flight.
// Wave-edge shuffles are replaced by 6 clamped scalar loads (same values,
// same cache lines as the float4 loads, branch-free load phase).
__global__ __launch_bounds__(256, 2) void bicon_loss_kernel(
    const float* __restrict__ c_map,
    const float* __restrict__ target,
    const float* __restrict__ con_target,
    float* __restrict__ out)
{
    const int tid  = threadIdx.x;
    const int lane = tid & 63;
    const int wave = tid >> 6;
    const int t    = blockIdx.x * 256 + tid;
    const int g    = t >> 7;          // global row id: 0 .. 16*512-1
    const int b    = g >> 9;
    const int row  = g & 511;
    const int px0  = (t & 127) << 2;  // 0..508, contiguous within a wave

    const bool hu = row > 0, hd = row < HH - 1;
    const bool wl = px0 > 0, wr = px0 < WW - 4;
    const int rU = hu ? row - 1 : 0;      // clamped; values gated at use
    const int rD = hd ? row + 1 : HH - 1;
    const int xl = wl ? px0 - 1 : px0;    // clamped; gated at use
    const int xr = wr ? px0 + 4 : px0;

    const float* base = c_map + b * CHW;
    const int ro = row * WW + px0;
    const float* cm = base + ro;
    const float* ct = con_target + b * CHW + ro;

    // ================= load phase: 23 x float4 + 6 scalars ==============
    float cv[8][4];
    #pragma unroll
    for (int c = 0; c < 8; ++c) ld4(cm + c * HW, cv[c]);

    float tvf[8][4];
    #pragma unroll
    for (int c = 0; c < 8; ++c) ld4(ct + c * HW, tvf[c]);

    float u5r[4], u6r[4], u7r[4], d0r[4], d1r[4], d2r[4];
    ld4(base + 5 * HW + rU * WW + px0, u5r);
    ld4(base + 6 * HW + rU * WW + px0, u6r);
    ld4(base + 7 * HW + rU * WW + px0, u7r);
    ld4(base + 0 * HW + rD * WW + px0, d0r);
    ld4(base + 1 * HW + rD * WW + px0, d1r);
    ld4(base + 2 * HW + rD * WW + px0, d2r);

    float tg[4];
    ld4(target + b * HW + ro, tg);

    // x-shift edge scalars (clamped addresses; same rows as float4 loads
    // above -> L1/L2 hits; value only consumed under wl/wr gates)
    const float u7p_r = base[7 * HW + rU  * WW + xl];  // c7[rU][px0-1]
    const float d0p_r = base[0 * HW + rD  * WW + xl];  // c0[rD][px0-1]
    const float m4p_r = base[4 * HW + row * WW + xl];  // c4[row][px0-1]
    const float u5n_r = base[5 * HW + rU  * WW + xr];  // c5[rU][px0+4]
    const float d2n_r = base[2 * HW + rD  * WW + xr];  // c2[rD][px0+4]
    const float m3n_r = base[3 * HW + row * WW + xr];  // c3[row][px0+4]

    __builtin_amdgcn_sched_barrier(0);   // nothing crosses: loads stay hoisted

    // ================= compute phase =================
    // center: sigmoid + fused conmap BCE, one exp+log per element
    //   -log2 p = log2(1+e), -log2(1-p) = c*log2e + log2(1+e), e = 2^(-c*log2e)
    float sp[8][4];
    int msk[4] = {0, 0, 0, 0};
    float acc_con = 0.0f;                       // log2 units
    #pragma unroll
    for (int c = 0; c < 8; ++c) {
        #pragma unroll
        for (int j = 0; j < 4; ++j) {
            const float cl2 = cv[c][j] * LOG2E;
            const float e   = __builtin_amdgcn_exp2f(-cl2);
            const float s   = 1.0f + e;
            const float Lg  = __builtin_amdgcn_logf(s);   // -log2(p)
            sp[c][j] = __builtin_amdgcn_rcpf(s);          // p
            const bool one = tvf[c][j] > 0.5f;
            msk[j] |= (int)one << c;
            acc_con += fminf(Lg + (one ? 0.0f : cl2), CLMP);
        }
    }

    const float sp4p = sigf(m4p_r);   // p(c4[row][px0-1])
    const float sp3n = sigf(m3n_r);   // p(c3[row][px0+4])

    float acc_bi = 0.0f, acc_de = 0.0f;         // log2 units
    #pragma unroll
    for (int j = 0; j < 4; ++j) {
        const float n6  = hu ? sigf(u6r[j]) : 0.0f;
        const float n5  = (((j < 3) ? hu : (hu && wr)))
                          ? sigf((j < 3) ? u5r[j + 1] : u5n_r) : 0.0f;
        const float n7  = (((j > 0) ? hu : (hu && wl)))
                          ? sigf((j > 0) ? u7r[j - 1] : u7p_r) : 0.0f;
        const float dn1 = hd ? sigf(d1r[j]) : 0.0f;
        const float dn2 = (((j < 3) ? hd : (hd && wr)))
                          ? sigf((j < 3) ? d2r[j + 1] : d2n_r) : 0.0f;
        const float dn0 = (((j > 0) ? hd : (hd && wl)))
                          ? sigf((j > 0) ? d0r[j - 1] : d0p_r) : 0.0f;
        const float m4  = (j > 0) ? sp[4][j - 1] : (wl ? sp4p : 0.0f);
        const float m3  = (j < 3) ? sp[3][j + 1] : (wr ? sp3n : 0.0f);

        const float a1 = sp[3][j] * m4;    // c3 * shift_right(c4)
        const float a2 = sp[4][j] * m3;    // c4 * shift_left(c3)
        const float a3 = sp[1][j] * n6;    // c1 * shift_down(c6)
        const float a4 = sp[6][j] * dn1;   // c6 * shift_up(c1)
        const float a5 = sp[2][j] * n5;    // c2 * left-bottom(c5)
        const float a6 = sp[5][j] * dn2;   // c5 * right-above(c2)
        const float a7 = sp[0][j] * n7;    // c0 * right-bottom(c7)
        const float a8 = sp[7][j] * dn0;   // c7 * left-above(c0)

        const float vote[8] = { a7, a3, a5, a1, a2, a6, a4, a8 };
        const int m = msk[j];

        #pragma unroll
        for (int c = 0; c < 8; ++c) {
            const bool one = (m >> c) & 1;
            const float q = one ? vote[c] : (1.0f - vote[c]);
            acc_bi += fminf(-__builtin_amdgcn_logf(q), CLMP);
        }

        const float glo = (a1 + a2 + a3 + a4 + a5 + a6 + a7 + a8) * 0.125f;
        float mn = vote[0];
        #pragma unroll
        for (int c = 1; c < 8; ++c) mn = fminf(mn, vote[c]);

        const bool edge = (m != 0) && (m != 255);
        const float dec = edge ? (1.0f - mn) : glo;
        const float qd  = (tg[j] > 0.5f) ? dec : (1.0f - dec);
        acc_de += fminf(-__builtin_amdgcn_logf(qd), CLMP);
    }

    float local = fmaf(0.8f, acc_con, fmaf(0.2f, acc_bi, acc_de)) * LN2;

    // ---- reduction: wave64 shuffle -> 4-float LDS -> one atomic ----
    #pragma unroll
    for (int off = 32; off > 0; off >>= 1)
        local += __shfl_down(local, off, 64);

    __shared__ float wsum[4];
    if (lane == 0) wsum[wave] = local;
    __syncthreads();
    if (tid == 0)
        atomicAdd(out, (wsum[0] + wsum[1]) + (wsum[2] + wsum[3]));
}

extern "C" void kernel_launch(void* const* d_in, const int* in_sizes, int n_in,
                              void* d_out, int out_size, void* d_ws, size_t ws_size,
                              hipStream_t stream) {
    const float* c_map      = (const float*)d_in[0];
    const float* target     = (const float*)d_in[1];
    const float* con_target = (const float*)d_in[2];
    float* out = (float*)d_out;

    hipMemsetAsync(out, 0, sizeof(float), stream);

    const int blocks = NB * (HH / 2);   // 4096 blocks x 256 thr, 4 px/thread
    bicon_loss_kernel<<<blocks, 256, 0, stream>>>(c_map, target, con_target, out);
}